// Round 2
// baseline (56.661 us; speedup 1.0000x reference)
//
#include <hip/hip_runtime.h>

#define BB 16
#define NN 6000
#define GG 512
#define RPT 3                     // ROIs per thread (independent dep chains)
#define ROIS_PER_BLOCK (64 * RPT) // 192

__global__ __launch_bounds__(64) void det_assign_kernel(
    const float4* __restrict__ rois,      // (B, N, 4)
    const int*    __restrict__ gt_ids,    // (B, G)
    const float4* __restrict__ gt_boxes,  // (B, G, 4)
    float*        __restrict__ out)       // [B*2*N maxes][B*N pos][B*N neg]
{
    __shared__ float4 s_box[GG];   // non-crowd from front, crowd from back
    __shared__ float  s_area[GG];
    __shared__ int    s_cnt[2];    // [0]=non-crowd count, [1]=crowd count

    const int b = blockIdx.y;

    if (threadIdx.x == 0) { s_cnt[0] = 0; s_cnt[1] = 0; }
    __syncthreads();

    // Compact valid GTs for this batch into LDS (order irrelevant for max).
    for (int g = threadIdx.x; g < GG; g += 64) {
        float4 box = gt_boxes[b * GG + g];
        float asum = fabsf(box.x) + fabsf(box.y) + fabsf(box.z) + fabsf(box.w);
        int id = gt_ids[b * GG + g];
        if (asum > 0.0f && id != 0) {
            int idx;
            if (id > 0) idx = atomicAdd(&s_cnt[0], 1);            // non-crowd: front
            else        idx = (GG - 1) - atomicAdd(&s_cnt[1], 1); // crowd: back
            s_box[idx]  = box;
            s_area[idx] = (box.z - box.x) * (box.w - box.y);
        }
    }
    __syncthreads();

    const int base = blockIdx.x * ROIS_PER_BLOCK + threadIdx.x;

    float4 r[RPT];
    float  rsum[RPT];   // rarea + eps (hoisted)
    bool   vroi[RPT];
    #pragma unroll
    for (int i = 0; i < RPT; ++i) {
        int n = base + i * 64;
        float4 rr = (n < NN) ? rois[b * NN + n] : make_float4(0.f, 0.f, 0.f, 0.f);
        r[i]    = rr;
        vroi[i] = (fabsf(rr.x) + fabsf(rr.y) + fabsf(rr.z) + fabsf(rr.w)) > 0.0f;
        rsum[i] = (rr.z - rr.x) * (rr.w - rr.y) + 1e-8f;
    }

    float ncm[RPT] = {0.f, 0.f, 0.f};
    float cm[RPT]  = {0.f, 0.f, 0.f};

    const int ncnt = s_cnt[0];
    const int ccnt = s_cnt[1];

    // Non-crowd max (uniform LDS address -> broadcast, conflict-free)
    for (int g = 0; g < ncnt; ++g) {
        float4 gb = s_box[g];
        float  ga = s_area[g];
        #pragma unroll
        for (int i = 0; i < RPT; ++i) {
            float yy1 = fmaxf(r[i].x, gb.x);
            float xx1 = fmaxf(r[i].y, gb.y);
            float yy2 = fminf(r[i].z, gb.z);
            float xx2 = fminf(r[i].w, gb.w);
            float inter = fmaxf(yy2 - yy1, 0.0f) * fmaxf(xx2 - xx1, 0.0f);
            float uni = rsum[i] + ga - inter;
            float iou = inter * __builtin_amdgcn_rcpf(uni);
            ncm[i] = fmaxf(ncm[i], iou);
        }
    }
    // Crowd max
    for (int g = GG - ccnt; g < GG; ++g) {
        float4 gb = s_box[g];
        float  ga = s_area[g];
        #pragma unroll
        for (int i = 0; i < RPT; ++i) {
            float yy1 = fmaxf(r[i].x, gb.x);
            float xx1 = fmaxf(r[i].y, gb.y);
            float yy2 = fminf(r[i].z, gb.z);
            float xx2 = fminf(r[i].w, gb.w);
            float inter = fmaxf(yy2 - yy1, 0.0f) * fmaxf(xx2 - xx1, 0.0f);
            float uni = rsum[i] + ga - inter;
            float iou = inter * __builtin_amdgcn_rcpf(uni);
            cm[i] = fmaxf(cm[i], iou);
        }
    }

    #pragma unroll
    for (int i = 0; i < RPT; ++i) {
        int n = base + i * 64;
        if (n >= NN) continue;
        float nc_max = vroi[i] ? ncm[i] : 0.0f;
        float c_max  = vroi[i] ? cm[i]  : 0.0f;

        out[b * 2 * NN + n]      = nc_max;           // iou_maxes (B,2,N) ch0
        out[b * 2 * NN + NN + n] = c_max;            // iou_maxes (B,2,N) ch1
        const float pos = (vroi[i] && nc_max >= 0.5f) ? 1.0f : 0.0f;
        const float neg = (vroi[i] && nc_max < 0.5f && c_max < 0.001f) ? 1.0f : 0.0f;
        out[BB * 2 * NN + b * NN + n]           = pos;
        out[BB * 2 * NN + BB * NN + b * NN + n] = neg;
    }
}

extern "C" void kernel_launch(void* const* d_in, const int* in_sizes, int n_in,
                              void* d_out, int out_size, void* d_ws, size_t ws_size,
                              hipStream_t stream) {
    const float4* rois     = (const float4*)d_in[0];
    const int*    gt_ids   = (const int*)d_in[1];
    const float4* gt_boxes = (const float4*)d_in[2];
    float*        out      = (float*)d_out;

    dim3 grid((NN + ROIS_PER_BLOCK - 1) / ROIS_PER_BLOCK, BB);  // 32 x 16 = 512 blocks
    det_assign_kernel<<<grid, 64, 0, stream>>>(rois, gt_ids, gt_boxes, out);
}

// Round 3
// 38.756 us; speedup vs baseline: 1.4620x; 1.4620x over previous
//
#include <hip/hip_runtime.h>

#define BB 16
#define NN 6000
#define GG 512

__global__ __launch_bounds__(64) void det_assign_kernel(
    const float4* __restrict__ rois,      // (B, N, 4)
    const int*    __restrict__ gt_ids,    // (B, G)
    const float4* __restrict__ gt_boxes,  // (B, G, 4)
    float*        __restrict__ out)       // [B*2*N maxes][B*N pos][B*N neg]
{
    __shared__ float4 s_box[GG];          // non-crowd from front, crowd from back
    __shared__ float4 s_area4[GG / 4];    // 16B-aligned areas for packed reads
    __shared__ int    s_cnt[2];           // [0]=non-crowd count, [1]=crowd count
    float* s_area = (float*)s_area4;

    const int b = blockIdx.y;

    if (threadIdx.x == 0) { s_cnt[0] = 0; s_cnt[1] = 0; }
    __syncthreads();

    // Compact valid GTs for this batch into LDS (order irrelevant for max).
    for (int g = threadIdx.x; g < GG; g += 64) {
        float4 box = gt_boxes[b * GG + g];
        float asum = fabsf(box.x) + fabsf(box.y) + fabsf(box.z) + fabsf(box.w);
        int id = gt_ids[b * GG + g];
        if (asum > 0.0f && id != 0) {
            int idx;
            if (id > 0) idx = atomicAdd(&s_cnt[0], 1);            // non-crowd: front
            else        idx = (GG - 1) - atomicAdd(&s_cnt[1], 1); // crowd: back
            s_box[idx]  = box;
            s_area[idx] = (box.z - box.x) * (box.w - box.y);
        }
    }
    __syncthreads();

    const int n = blockIdx.x * 64 + threadIdx.x;
    if (n >= NN) return;

    const float4 r = rois[b * NN + n];
    const bool vroi = (fabsf(r.x) + fabsf(r.y) + fabsf(r.z) + fabsf(r.w)) > 0.0f;
    const float rsum = (r.z - r.x) * (r.w - r.y) + 1e-8f;  // rarea + eps hoisted

    // Uniform loop bounds in SGPR -> scalar loop control
    const int ncnt = __builtin_amdgcn_readfirstlane(s_cnt[0]);
    const int ccnt = __builtin_amdgcn_readfirstlane(s_cnt[1]);

    auto iou_of = [&](float4 gb, float ga) -> float {
        float yy1 = fmaxf(r.x, gb.x);
        float xx1 = fmaxf(r.y, gb.y);
        float yy2 = fminf(r.z, gb.z);
        float xx2 = fminf(r.w, gb.w);
        float inter = fmaxf(yy2 - yy1, 0.0f) * fmaxf(xx2 - xx1, 0.0f);
        float uni = rsum + ga - inter;
        return inter * __builtin_amdgcn_rcpf(uni);
    };

    float ncm = 0.0f;
    {
        int g = 0;
        const int n4 = ncnt & ~3;
        for (; g < n4; g += 4) {
            float4 b0 = s_box[g + 0];
            float4 b1 = s_box[g + 1];
            float4 b2 = s_box[g + 2];
            float4 b3 = s_box[g + 3];
            float4 a4 = s_area4[g >> 2];
            float i0 = iou_of(b0, a4.x);
            float i1 = iou_of(b1, a4.y);
            float i2 = iou_of(b2, a4.z);
            float i3 = iou_of(b3, a4.w);
            ncm = fmaxf(ncm, fmaxf(fmaxf(i0, i1), fmaxf(i2, i3)));
        }
        for (; g < ncnt; ++g) ncm = fmaxf(ncm, iou_of(s_box[g], s_area[g]));
    }

    float cm = 0.0f;
    {
        const int lo = GG - ccnt;
        int g = GG;
        while (g - 4 >= lo) {
            g -= 4;
            float4 b0 = s_box[g + 0];
            float4 b1 = s_box[g + 1];
            float4 b2 = s_box[g + 2];
            float4 b3 = s_box[g + 3];
            float4 a4 = s_area4[g >> 2];
            float i0 = iou_of(b0, a4.x);
            float i1 = iou_of(b1, a4.y);
            float i2 = iou_of(b2, a4.z);
            float i3 = iou_of(b3, a4.w);
            cm = fmaxf(cm, fmaxf(fmaxf(i0, i1), fmaxf(i2, i3)));
        }
        while (g > lo) { --g; cm = fmaxf(cm, iou_of(s_box[g], s_area[g])); }
    }

    const float nc_max = vroi ? ncm : 0.0f;
    const float c_max  = vroi ? cm  : 0.0f;

    out[b * 2 * NN + n]      = nc_max;     // iou_maxes (B,2,N) ch0
    out[b * 2 * NN + NN + n] = c_max;      // iou_maxes (B,2,N) ch1
    const float pos = (vroi && nc_max >= 0.5f) ? 1.0f : 0.0f;
    const float neg = (vroi && nc_max < 0.5f && c_max < 0.001f) ? 1.0f : 0.0f;
    out[BB * 2 * NN + b * NN + n]           = pos;
    out[BB * 2 * NN + BB * NN + b * NN + n] = neg;
}

extern "C" void kernel_launch(void* const* d_in, const int* in_sizes, int n_in,
                              void* d_out, int out_size, void* d_ws, size_t ws_size,
                              hipStream_t stream) {
    const float4* rois     = (const float4*)d_in[0];
    const int*    gt_ids   = (const int*)d_in[1];
    const float4* gt_boxes = (const float4*)d_in[2];
    float*        out      = (float*)d_out;

    dim3 grid((NN + 63) / 64, BB);  // 94 x 16 = 1504 one-wave blocks
    det_assign_kernel<<<grid, 64, 0, stream>>>(rois, gt_ids, gt_boxes, out);
}

// Round 4
// 27.058 us; speedup vs baseline: 2.0940x; 1.4323x over previous
//
#include <hip/hip_runtime.h>

#define BB 16
#define NN 6000
#define GG 512

__global__ __launch_bounds__(256) void det_assign_kernel(
    const float4* __restrict__ rois,      // (B, N, 4)
    const int*    __restrict__ gt_ids,    // (B, G)
    const float4* __restrict__ gt_boxes,  // (B, G, 4)
    float*        __restrict__ out)       // [B*2*N maxes][B*N pos][B*N neg]
{
    __shared__ float4 s_box[GG];          // non-crowd from front, crowd from back
    __shared__ float4 s_area4[GG / 4];    // 16B-aligned areas for packed reads
    __shared__ float  s_ncm[4][64];       // per-wave partial maxes
    __shared__ float  s_cm[4][64];
    __shared__ int    s_cnt[2];           // [0]=non-crowd count, [1]=crowd count
    float* s_area = (float*)s_area4;

    const int b    = blockIdx.y;
    const int tid  = threadIdx.x;
    const int wave = tid >> 6;
    const int lane = tid & 63;

    if (tid == 0) { s_cnt[0] = 0; s_cnt[1] = 0; }
    __syncthreads();

    // Compact valid GTs for this batch into LDS (order irrelevant for max).
    for (int g = tid; g < GG; g += 256) {
        float4 box = gt_boxes[b * GG + g];
        float asum = fabsf(box.x) + fabsf(box.y) + fabsf(box.z) + fabsf(box.w);
        int id = gt_ids[b * GG + g];
        if (asum > 0.0f && id != 0) {
            int idx;
            if (id > 0) idx = atomicAdd(&s_cnt[0], 1);            // non-crowd: front
            else        idx = (GG - 1) - atomicAdd(&s_cnt[1], 1); // crowd: back
            s_box[idx]  = box;
            s_area[idx] = (box.z - box.x) * (box.w - box.y);
        }
    }
    __syncthreads();

    // All 4 waves process the SAME 64 ROIs; each wave takes a quarter of G.
    const int n = blockIdx.x * 64 + lane;
    const float4 r = (n < NN) ? rois[b * NN + n] : make_float4(0.f, 0.f, 0.f, 0.f);
    const bool vroi = (fabsf(r.x) + fabsf(r.y) + fabsf(r.z) + fabsf(r.w)) > 0.0f;
    const float rsum = (r.z - r.x) * (r.w - r.y) + 1e-8f;

    const int ncnt = __builtin_amdgcn_readfirstlane(s_cnt[0]);
    const int ccnt = __builtin_amdgcn_readfirstlane(s_cnt[1]);

    auto iou_of = [&](float4 gb, float ga) -> float {
        float yy1 = fmaxf(r.x, gb.x);
        float xx1 = fmaxf(r.y, gb.y);
        float yy2 = fminf(r.z, gb.z);
        float xx2 = fminf(r.w, gb.w);
        float inter = fmaxf(yy2 - yy1, 0.0f) * fmaxf(xx2 - xx1, 0.0f);
        float uni = rsum + ga - inter;
        return inter * __builtin_amdgcn_rcpf(uni);
    };

    // --- Non-crowd: wave takes contiguous, 4-aligned chunk of [0, ncnt) ---
    float ncm = 0.0f;
    {
        const int chunk = (((ncnt + 3) >> 2) + 3) & ~3;       // align-up(ceil/4, 4)
        const int g0 = wave * chunk;
        const int g1 = min(ncnt, g0 + chunk);
        int g = g0;
        for (; g + 4 <= g1; g += 4) {
            float4 b0 = s_box[g + 0];
            float4 b1 = s_box[g + 1];
            float4 b2 = s_box[g + 2];
            float4 b3 = s_box[g + 3];
            float4 a4 = s_area4[g >> 2];
            float i0 = iou_of(b0, a4.x);
            float i1 = iou_of(b1, a4.y);
            float i2 = iou_of(b2, a4.z);
            float i3 = iou_of(b3, a4.w);
            ncm = fmaxf(ncm, fmaxf(fmaxf(i0, i1), fmaxf(i2, i3)));
        }
        for (; g < g1; ++g) ncm = fmaxf(ncm, iou_of(s_box[g], s_area[g]));
    }

    // --- Crowd: list occupies [GG-ccnt, GG); wave takes descending chunk ---
    float cm = 0.0f;
    {
        const int chunkc = (((ccnt + 3) >> 2) + 3) & ~3;
        const int hi = GG - wave * chunkc;                    // multiple of 4
        const int lo = max(GG - ccnt, hi - chunkc);
        int g = hi;
        while (g - 4 >= lo) {
            g -= 4;
            float4 b0 = s_box[g + 0];
            float4 b1 = s_box[g + 1];
            float4 b2 = s_box[g + 2];
            float4 b3 = s_box[g + 3];
            float4 a4 = s_area4[g >> 2];
            float i0 = iou_of(b0, a4.x);
            float i1 = iou_of(b1, a4.y);
            float i2 = iou_of(b2, a4.z);
            float i3 = iou_of(b3, a4.w);
            cm = fmaxf(cm, fmaxf(fmaxf(i0, i1), fmaxf(i2, i3)));
        }
        while (g > lo) { --g; cm = fmaxf(cm, iou_of(s_box[g], s_area[g])); }
    }

    s_ncm[wave][lane] = ncm;
    s_cm[wave][lane]  = cm;
    __syncthreads();

    if (wave == 0 && n < NN) {
        float a = fmaxf(fmaxf(s_ncm[0][lane], s_ncm[1][lane]),
                        fmaxf(s_ncm[2][lane], s_ncm[3][lane]));
        float c = fmaxf(fmaxf(s_cm[0][lane], s_cm[1][lane]),
                        fmaxf(s_cm[2][lane], s_cm[3][lane]));
        const float nc_max = vroi ? a : 0.0f;
        const float c_max  = vroi ? c : 0.0f;

        out[b * 2 * NN + n]      = nc_max;     // iou_maxes (B,2,N) ch0
        out[b * 2 * NN + NN + n] = c_max;      // iou_maxes (B,2,N) ch1
        const float pos = (vroi && nc_max >= 0.5f) ? 1.0f : 0.0f;
        const float neg = (vroi && nc_max < 0.5f && c_max < 0.001f) ? 1.0f : 0.0f;
        out[BB * 2 * NN + b * NN + n]           = pos;
        out[BB * 2 * NN + BB * NN + b * NN + n] = neg;
    }
}

extern "C" void kernel_launch(void* const* d_in, const int* in_sizes, int n_in,
                              void* d_out, int out_size, void* d_ws, size_t ws_size,
                              hipStream_t stream) {
    const float4* rois     = (const float4*)d_in[0];
    const int*    gt_ids   = (const int*)d_in[1];
    const float4* gt_boxes = (const float4*)d_in[2];
    float*        out      = (float*)d_out;

    dim3 grid((NN + 63) / 64, BB);  // 94 x 16 = 1504 blocks, 4 waves each
    det_assign_kernel<<<grid, 256, 0, stream>>>(rois, gt_ids, gt_boxes, out);
}